// Round 4
// baseline (355.042 us; speedup 1.0000x reference)
//
#include <hip/hip_runtime.h>
#include <math.h>

// Problem constants (fixed by the reference)
#define BATCH 65536
#define DIM 128
#define NBAS 6
#define OUTW 896              // DIM*NBAS + DIM
#define ROWS_PER_TILE 32
#define LDS_F4 33             // float4 stride per LDS row (32 + 1 pad)
#define LDS_F 132             // float stride per LDS row

typedef float f4v __attribute__((ext_vector_type(4)));

// ---------------------------------------------------------------------------
// Kernel 1: S = sigmoid(W), 128x128 into workspace. Trivial.
// ---------------------------------------------------------------------------
__global__ __launch_bounds__(256) void sigmoid_k(const float* __restrict__ W,
                                                 float* __restrict__ S) {
    int t = blockIdx.x * 256 + threadIdx.x;
    float w = W[t];
    S[t] = 1.0f / (1.0f + expf(-w));
}

// ---------------------------------------------------------------------------
// Closed-form uniform cubic B-spline weights (identical math to the
// Cox-de Boor ladder for knots = linspace(-1,1,10)).
// ---------------------------------------------------------------------------
__device__ __forceinline__ void bw(float x, int& s,
                                   float& w0, float& w1, float& w2, float& w3) {
    const float i6 = 0.16666666666666666f;
    float xc = fminf(fmaxf(x, -1.0f), 1.0f - 1e-6f);
    float p  = (xc + 1.0f) * 4.5f;
    float sf = floorf(p);
    float u  = p - sf;
    s = (int)sf;                       // 0..8
    float u2 = u * u;
    float v  = 1.0f - u;
    w0 = u * u2 * i6;                                       // t = s
    w1 = (((-3.0f * u + 3.0f) * u + 3.0f) * u + 1.0f) * i6; // t = s-1
    w2 = ((3.0f * u - 6.0f) * u2 + 4.0f) * i6;              // t = s-2
    w3 = v * v * v * i6;                                    // t = s-3
}

// value of basis index t = s-d, branch-free (d outside [0,3] -> 0)
__device__ __forceinline__ float pick4(float w0, float w1, float w2, float w3, int d) {
    float r = 0.0f;
    r = (d == 0) ? w0 : r;
    r = (d == 1) ? w1 : r;
    r = (d == 2) ? w2 : r;
    r = (d == 3) ? w3 : r;
    return r;
}

// ---------------------------------------------------------------------------
// Main fused kernel — IDENTICAL memory/compute structure to round 3.
// A pure-register dependent-FMA pad is appended at the end to push this
// dispatch above the ~146us poison fills so rocprof's top-5 finally shows
// kan_main's own FETCH/WRITE/VALUBusy/VGPR counters. The pad touches no
// memory (asm-sink keeps it live, guide rule #17) and will be removed next
// round once the bottleneck hypothesis is discriminated.
// ---------------------------------------------------------------------------
__global__ __launch_bounds__(256, 8) void kan_main(const float* __restrict__ X,
                                                   const float* __restrict__ S,
                                                   float* __restrict__ out) {
    __shared__ __align__(16) float xTf[ROWS_PER_TILE * LDS_F];  // 16.9 KB

    const int tid = threadIdx.x;
    const int row0 = blockIdx.x * ROWS_PER_TILE;

    // ---------------- Phase 0: stage x row-major (straight copy) ----------
    const float4* X4 = (const float4*)(X + (size_t)row0 * DIM);
    float4* xT4 = (float4*)xTf;
#pragma unroll
    for (int k = 0; k < 4; ++k) {
        int e4 = k * 256 + tid;      // float4 index in tile, 0..1023
        int r = e4 >> 5;             // row within tile (0..31)
        int i4 = e4 & 31;            // float4 within row
        xT4[r * LDS_F4 + i4] = X4[e4];
    }
    __syncthreads();

    // ---------------- Phase 1: interaction GEMM ----------------
    {
        const int c = tid & 31;          // col group: cols 4c..4c+3
        const int r0 = (tid >> 5) * 4;   // rows r0..r0+3

        float acc[4][4];
#pragma unroll
        for (int rr = 0; rr < 4; ++rr)
#pragma unroll
            for (int q = 0; q < 4; ++q) acc[rr][q] = 0.0f;

        const float4* S4 = (const float4*)S;
        const float* xp0 = xTf + (r0 + 0) * LDS_F;
        const float* xp1 = xTf + (r0 + 1) * LDS_F;
        const float* xp2 = xTf + (r0 + 2) * LDS_F;
        const float* xp3 = xTf + (r0 + 3) * LDS_F;
#pragma unroll 2
        for (int i = 0; i < DIM; ++i) {
            float4 s = S4[i * 32 + c];       // L2-resident, coalesced
            float x0 = xp0[i], x1 = xp1[i], x2 = xp2[i], x3 = xp3[i];  // broadcasts
            float xq[4] = {x0 * x0, x1 * x1, x2 * x2, x3 * x3};
#pragma unroll
            for (int rr = 0; rr < 4; ++rr) {
#pragma unroll
                for (int q = 0; q < 4; ++q) {
                    float sv = (q == 0) ? s.x : (q == 1) ? s.y : (q == 2) ? s.z : s.w;
                    acc[rr][q] = fmaf(xq[rr], sv, acc[rr][q]);
                }
            }
        }

#pragma unroll
        for (int rr = 0; rr < 4; ++rr) {
            f4v v = {acc[rr][0], acc[rr][1], acc[rr][2], acc[rr][3]};
            __builtin_nontemporal_store(
                v, (f4v*)(out + (size_t)(row0 + r0 + rr) * OUTW + DIM * NBAS + 4 * c));
        }
    }

    // ---------------- Phase 2: basis, coalesced-by-output ----------------
    {
        const int lane = tid & 63;
        const int wv = tid >> 6;

        int fAh[3], fBh[3], tbh[3];
        bool uBh[3];
#pragma unroll
        for (int t = 0; t < 3; ++t) {
            int j = t * 64 + lane;           // float4 idx in row, 0..191
            int m = j % 3;                   // straddle pattern
            int o0 = 4 * j;                  // first out float
            int fA = o0 / 6;                 // 0..127
            fAh[t] = fA;
            fBh[t] = (fA < 127) ? fA + 1 : 127;
            tbh[t] = (m == 0) ? 0 : (m == 2) ? 2 : 4;
            uBh[t] = (m == 1);
        }

#pragma unroll 2
        for (int rr = 0; rr < 8; ++rr) {
            int r = rr * 4 + wv;             // waves cover adjacent rows together
            const float* xrow = xTf + r * LDS_F;
            float* orow = out + (size_t)(row0 + r) * OUTW;
#pragma unroll
            for (int t = 0; t < 3; ++t) {
                float xA = xrow[fAh[t]];
                float xB = xrow[fBh[t]];
                int sA, sB;
                float a0, a1, a2, a3, b0, b1, b2, b3;
                bw(xA, sA, a0, a1, a2, a3);
                bw(xB, sB, b0, b1, b2, b3);
                int dA = sA - tbh[t];
                float r0v = pick4(a0, a1, a2, a3, dA);
                float r1v = pick4(a0, a1, a2, a3, dA - 1);
                float r2v = uBh[t] ? pick4(b0, b1, b2, b3, sB)
                                   : pick4(a0, a1, a2, a3, dA - 2);
                float r3v = uBh[t] ? pick4(b0, b1, b2, b3, sB - 1)
                                   : pick4(a0, a1, a2, a3, dA - 3);
                f4v v = {r0v, r1v, r2v, r3v};
                __builtin_nontemporal_store(v, (f4v*)(orow + 4 * (t * 64 + lane)));
            }
        }
    }

    // ---- TEMPORARY diagnostic pad (counter-surfacing; REMOVE next round) ----
    // 2500 dependent FMAs in registers, seeded from LDS (data-dependent, not
    // foldable), sunk into an asm sink (not DCE-able). Adds ~4-17us of pure
    // VALU tail so this dispatch outranks the ~146us harness fills in the
    // top-5 table and exposes kan_main's FETCH/WRITE/VALUBusy/VGPR counters.
    {
        float z = xTf[tid];
#pragma unroll 1
        for (int it = 0; it < 2500; ++it)
            z = __builtin_fmaf(z, 1.0000000001f, 1e-38f);
        asm volatile("" :: "v"(z));
    }
}

// ---------------------------------------------------------------------------
extern "C" void kernel_launch(void* const* d_in, const int* in_sizes, int n_in,
                              void* d_out, int out_size, void* d_ws, size_t ws_size,
                              hipStream_t stream) {
    const float* X = (const float*)d_in[0];
    const float* W = (const float*)d_in[1];
    float* out = (float*)d_out;
    float* S = (float*)d_ws;   // 64 KB scratch for sigmoid(W)

    sigmoid_k<<<(DIM * DIM) / 256, 256, 0, stream>>>(W, S);
    kan_main<<<BATCH / ROWS_PER_TILE, 256, 0, stream>>>(X, S, out);
}

// Round 5
// 284.487 us; speedup vs baseline: 1.2480x; 1.2480x over previous
//
#include <hip/hip_runtime.h>
#include <math.h>

// Problem constants (fixed by the reference)
#define BATCH 65536
#define DIM 128
#define NBAS 6
#define OUTW 896              // DIM*NBAS + DIM
#define ROWS_PER_TILE 32
#define CHROWS 8              // rows per basis LDS chunk
#define NCHUNK 4              // 32 rows / 8
#define XT_F 128              // x tile row stride (floats) == DIM (linear copy)
#define BAS_F 768             // basis row stride (floats) = DIM*NBAS

typedef float f4v __attribute__((ext_vector_type(4)));

// ---------------------------------------------------------------------------
// Kernel 1: S = sigmoid(W), 128x128 into workspace. Trivial.
// ---------------------------------------------------------------------------
__global__ __launch_bounds__(256) void sigmoid_k(const float* __restrict__ W,
                                                 float* __restrict__ S) {
    int t = blockIdx.x * 256 + threadIdx.x;
    float w = W[t];
    S[t] = 1.0f / (1.0f + expf(-w));
}

// ---------------------------------------------------------------------------
// Closed-form uniform cubic B-spline weights (identical math to the
// Cox-de Boor ladder for knots = linspace(-1,1,10)).
// Nonzero basis entries are slots t = s-3..s (clipped to [0,5]) with
// weights w3..w0.
// ---------------------------------------------------------------------------
__device__ __forceinline__ void bw(float x, int& s,
                                   float& w0, float& w1, float& w2, float& w3) {
    const float i6 = 0.16666666666666666f;
    float xc = fminf(fmaxf(x, -1.0f), 1.0f - 1e-6f);
    float p  = (xc + 1.0f) * 4.5f;
    float sf = floorf(p);
    float u  = p - sf;
    s = (int)sf;                       // 0..8
    float u2 = u * u;
    float v  = 1.0f - u;
    w0 = u * u2 * i6;                                       // t = s
    w1 = (((-3.0f * u + 3.0f) * u + 3.0f) * u + 1.0f) * i6; // t = s-1
    w2 = ((3.0f * u - 6.0f) * u2 + 4.0f) * i6;              // t = s-2
    w3 = v * v * v * i6;                                    // t = s-3
}

// ---------------------------------------------------------------------------
// Main fused kernel. 32-row tiles, 2048 blocks. LDS = 16KB x-tile + 24KB
// basis chunk = 40KB -> 4 blocks/CU (16 waves/CU).
//
// Counters (r4 pad probe) showed: traffic nominal (WRITE=229.6MB), HBM 17%,
// 0 bank conflicts, no spill -> kernel is instruction-ISSUE bound. The old
// basis phase burned ~65+ VALU per float4 on select chains (pick4 = cmp+
// cndmask x8 per slot). This version replaces selection with LDS SCATTER:
// per feature, one bw() (14 VALU) + <=4 predicated ds_write_b32 at
// [f*6 + s - d] into a zeroed chunk; runtime placement is free via the
// address path. Copy-out is contiguous b128 reads -> coalesced NT stores.
// GEMM phase deliberately unchanged (single-variable experiment).
// ---------------------------------------------------------------------------
__global__ __launch_bounds__(256, 4) void kan_main(const float* __restrict__ X,
                                                   const float* __restrict__ S,
                                                   float* __restrict__ out) {
    __shared__ __align__(16) float xTf[ROWS_PER_TILE * XT_F];  // 16 KB
    __shared__ __align__(16) float bas[CHROWS * BAS_F];        // 24 KB

    const int tid = threadIdx.x;
    const int row0 = blockIdx.x * ROWS_PER_TILE;

    // ---------------- Phase 0: stage x (linear copy) + zero bas ----------
    const float4* X4 = (const float4*)(X + (size_t)row0 * DIM);
    float4* xT4 = (float4*)xTf;
#pragma unroll
    for (int k = 0; k < 4; ++k) {
        int e4 = k * 256 + tid;          // 1024 float4s, stride == global
        xT4[e4] = X4[e4];
    }
    f4v z4 = {0.0f, 0.0f, 0.0f, 0.0f};
    f4v* bas4 = (f4v*)bas;
#pragma unroll
    for (int k = 0; k < 6; ++k) bas4[k * 256 + tid] = z4;      // 1536 f4
    __syncthreads();

    // ---------------- Phase 1: interaction GEMM (unchanged) ----------------
    {
        const int c = tid & 31;          // col group: cols 4c..4c+3
        const int r0 = (tid >> 5) * 4;   // rows r0..r0+3

        float acc[4][4];
#pragma unroll
        for (int rr = 0; rr < 4; ++rr)
#pragma unroll
            for (int q = 0; q < 4; ++q) acc[rr][q] = 0.0f;

        const float4* S4 = (const float4*)S;
        const float* xp0 = xTf + (r0 + 0) * XT_F;
        const float* xp1 = xTf + (r0 + 1) * XT_F;
        const float* xp2 = xTf + (r0 + 2) * XT_F;
        const float* xp3 = xTf + (r0 + 3) * XT_F;
#pragma unroll 2
        for (int i = 0; i < DIM; ++i) {
            float4 s = S4[i * 32 + c];       // L2-resident, coalesced
            float x0 = xp0[i], x1 = xp1[i], x2 = xp2[i], x3 = xp3[i];  // broadcasts
            float xq[4] = {x0 * x0, x1 * x1, x2 * x2, x3 * x3};
#pragma unroll
            for (int rr = 0; rr < 4; ++rr) {
#pragma unroll
                for (int q = 0; q < 4; ++q) {
                    float sv = (q == 0) ? s.x : (q == 1) ? s.y : (q == 2) ? s.z : s.w;
                    acc[rr][q] = fmaf(xq[rr], sv, acc[rr][q]);
                }
            }
        }

#pragma unroll
        for (int rr = 0; rr < 4; ++rr) {
            f4v v = {acc[rr][0], acc[rr][1], acc[rr][2], acc[rr][3]};
            __builtin_nontemporal_store(
                v, (f4v*)(out + (size_t)(row0 + r0 + rr) * OUTW + DIM * NBAS + 4 * c));
        }
    }
    // No barrier needed here: GEMM touches xTf (read) and out[.,768:] only;
    // scatter below touches bas (already zeroed before the first barrier).

    // ---------------- Phase 2: basis via LDS scatter ----------------
    // Chunk of 8 rows: 32 threads/row, 4 features per thread.
    {
        const int sr = tid >> 5;             // chunk-local row 0..7
        const int f0 = tid & 31;
        for (int c = 0; c < NCHUNK; ++c) {
            const float* xrow = xTf + (c * CHROWS + sr) * XT_F;
            float* basr = bas + sr * BAS_F;
#pragma unroll
            for (int m = 0; m < 4; ++m) {
                int f = f0 + 32 * m;
                float x = xrow[f];
                int s;
                float w0, w1, w2, w3;
                bw(x, s, w0, w1, w2, w3);
                float* bp = basr + f * NBAS + s;
                // slot t = s-d must lie in [0,5]; out-of-range weights are
                // dropped (matches the reference's truncated knot vector).
                if (s <= 5)           bp[0]  = w0;
                if (s >= 1 && s <= 6) bp[-1] = w1;
                if (s >= 2 && s <= 7) bp[-2] = w2;
                if (s >= 3)           bp[-3] = w3;   // s<=8 always
            }
            __syncthreads();

            // copy-out + re-zero (thread re-zeroes exactly the f4 it read,
            // so no intra-barrier race).
            float* ob = out + (size_t)(row0 + c * CHROWS) * OUTW;
#pragma unroll
            for (int k = 0; k < 6; ++k) {
                int idx = k * 256 + tid;     // f4 idx in chunk, 0..1535
                int r = idx / 192;           // 192 f4 per row
                int j = idx - r * 192;
                f4v v = bas4[idx];
                __builtin_nontemporal_store(v, (f4v*)(ob + (size_t)r * OUTW + 4 * j));
                bas4[idx] = z4;
            }
            __syncthreads();
        }
    }
}

// ---------------------------------------------------------------------------
extern "C" void kernel_launch(void* const* d_in, const int* in_sizes, int n_in,
                              void* d_out, int out_size, void* d_ws, size_t ws_size,
                              hipStream_t stream) {
    const float* X = (const float*)d_in[0];
    const float* W = (const float*)d_in[1];
    float* out = (float*)d_out;
    float* S = (float*)d_ws;   // 64 KB scratch for sigmoid(W)

    sigmoid_k<<<(DIM * DIM) / 256, 256, 0, stream>>>(W, S);
    kan_main<<<BATCH / ROWS_PER_TILE, 256, 0, stream>>>(X, S, out);
}

// Round 6
// 269.816 us; speedup vs baseline: 1.3159x; 1.0544x over previous
//
#include <hip/hip_runtime.h>
#include <math.h>

// Problem constants (fixed by the reference)
#define BATCH 65536
#define DIM 128
#define NBAS 6
#define OUTW 896              // DIM*NBAS + DIM
#define ROWS_PER_TILE 32
#define CHROWS 8              // rows per basis LDS chunk
#define NCHUNK 4              // 32 rows / 8
#define XT_F 128              // x tile row stride (floats), linear
#define BAS_F 768             // basis row stride (floats) = DIM*NBAS

typedef float f4v __attribute__((ext_vector_type(4)));
typedef float f32x4 __attribute__((ext_vector_type(4)));
typedef _Float16 f16x4 __attribute__((ext_vector_type(4)));
typedef _Float16 f16x8 __attribute__((ext_vector_type(8)));

// ---------------------------------------------------------------------------
// Kernel 1: ST = sigmoid(W)^T in fp16 (ST[j][i] = sigmoid(W[i][j])).
// B^T row-major layout so MFMA B-fragments are k-contiguous 16B loads.
// ---------------------------------------------------------------------------
__global__ __launch_bounds__(256) void sigmoid_kT(const float* __restrict__ W,
                                                  _Float16* __restrict__ ST) {
    int t = blockIdx.x * 256 + threadIdx.x;
    int i = t >> 7;            // W row
    int j = t & 127;           // W col
    float w = W[t];
    float s = 1.0f / (1.0f + expf(-w));
    ST[j * 128 + i] = (_Float16)s;
}

// ---------------------------------------------------------------------------
// Closed-form uniform cubic B-spline weights (identical math to the
// Cox-de Boor ladder for knots = linspace(-1,1,10)).
// ---------------------------------------------------------------------------
__device__ __forceinline__ void bw(float x, int& s,
                                   float& w0, float& w1, float& w2, float& w3) {
    const float i6 = 0.16666666666666666f;
    float xc = fminf(fmaxf(x, -1.0f), 1.0f - 1e-6f);
    float p  = (xc + 1.0f) * 4.5f;
    float sf = floorf(p);
    float u  = p - sf;
    s = (int)sf;                       // 0..8
    float u2 = u * u;
    float v  = 1.0f - u;
    w0 = u * u2 * i6;                                       // t = s
    w1 = (((-3.0f * u + 3.0f) * u + 3.0f) * u + 1.0f) * i6; // t = s-1
    w2 = ((3.0f * u - 6.0f) * u2 + 4.0f) * i6;              // t = s-2
    w3 = v * v * v * i6;                                    // t = s-3
}

// ---------------------------------------------------------------------------
// Main fused kernel. 32-row tiles, 2048 blocks. LDS = 16KB x(f32) + 8KB
// x^2(fp16, XOR-swizzled) + 24KB basis chunk = 48KB -> 3 blocks/CU.
//
// r4 pad probe: traffic nominal, HBM 17%, 0 conflicts, VALUBusy ~37% —
// and the pad ran 2.5x its issue cost => effective clock ~1GHz, kernel is
// instruction-issue bound with GEMM = ~85% of instructions. This version
// moves the GEMM to MFMA (fp16 in, f32 acc): 16 mfma/wave replace 2048
// scalar FMAs/thread. Basis scatter phase verbatim from round 5.
// ---------------------------------------------------------------------------
__global__ __launch_bounds__(256, 3) void kan_main(const float* __restrict__ X,
                                                   const _Float16* __restrict__ ST,
                                                   float* __restrict__ out) {
    __shared__ __align__(16) float xTf[ROWS_PER_TILE * XT_F];     // 16 KB
    __shared__ __align__(16) _Float16 xsq[ROWS_PER_TILE * 128];   // 8 KB, swizzled
    __shared__ __align__(16) float bas[CHROWS * BAS_F];           // 24 KB

    const int tid = threadIdx.x;
    const int row0 = blockIdx.x * ROWS_PER_TILE;

    // ---------------- Phase 0: stage x (f32 linear) + x^2 (fp16 swizzled)
    //                  + zero bas ----------
    const float4* X4 = (const float4*)(X + (size_t)row0 * DIM);
    float4* xT4 = (float4*)xTf;
#pragma unroll
    for (int k = 0; k < 4; ++k) {
        int e4 = k * 256 + tid;          // 1024 float4s, linear
        int r = e4 >> 5;                 // row 0..31
        int i4 = e4 & 31;                // float4 within row
        float4 xv = X4[e4];
        xT4[e4] = xv;
        f16x4 q = {(_Float16)(xv.x * xv.x), (_Float16)(xv.y * xv.y),
                   (_Float16)(xv.z * xv.z), (_Float16)(xv.w * xv.w)};
        // row-major [32][128] fp16 (256B/row), byte XOR-swizzled so MFMA
        // A-fragment ds_read_b128 (16 rows, same k-slice) is conflict-free.
        int byte = (r * 256 + i4 * 8) ^ ((r & 7) << 4);
        *(f16x4*)((char*)xsq + byte) = q;
    }
    f4v z4 = {0.0f, 0.0f, 0.0f, 0.0f};
    f4v* bas4 = (f4v*)bas;
#pragma unroll
    for (int k = 0; k < 6; ++k) bas4[k * 256 + tid] = z4;      // 1536 f4
    __syncthreads();

    // ---------------- Phase 1: interaction GEMM via MFMA ----------------
    // out[r][j] = sum_i x2[r][i] * S[i][j].  A = x2 (M=32,K=128) from LDS;
    // B-frags from ST (B^T rows, k-contiguous) in L2.  Wave w: rows
    // (w&1)*16..+15, cols (w>>1)*64..+63 (4 col-tiles x 4 K-steps = 16 MFMA).
    {
        const int w = tid >> 6, l = tid & 63;
        const int lr = l & 15, lg = l >> 4;
        const int rt = w & 1;
        const int ch = w >> 1;

        f16x8 af[4];
#pragma unroll
        for (int kk = 0; kk < 4; ++kk) {
            int byte = ((rt * 16 + lr) * 256 + kk * 64 + lg * 16) ^ ((lr & 7) << 4);
            af[kk] = *(const f16x8*)((const char*)xsq + byte);
        }

        f32x4 acc[4];
#pragma unroll
        for (int ct = 0; ct < 4; ++ct) acc[ct] = (f32x4){0.f, 0.f, 0.f, 0.f};

        const char* stb = (const char*)ST;
#pragma unroll
        for (int ct = 0; ct < 4; ++ct) {
            const char* bp = stb + (ch * 64 + ct * 16 + lr) * 256 + lg * 16;
#pragma unroll
            for (int kk = 0; kk < 4; ++kk) {
                f16x8 bf = *(const f16x8*)(bp + kk * 64);
                acc[ct] = __builtin_amdgcn_mfma_f32_16x16x32_f16(af[kk], bf, acc[ct], 0, 0, 0);
            }
        }

        // C layout (m89-verified): n = lane&15, m = (lane>>4)*4 + reg.
#pragma unroll
        for (int ct = 0; ct < 4; ++ct) {
            int colb = ch * 64 + ct * 16 + lr;
#pragma unroll
            for (int q = 0; q < 4; ++q) {
                int rowi = rt * 16 + lg * 4 + q;
                __builtin_nontemporal_store(
                    acc[ct][q],
                    out + (size_t)(row0 + rowi) * OUTW + DIM * NBAS + colb);
            }
        }
    }
    // No barrier needed: GEMM read xsq (written before the barrier above);
    // scatter below touches bas only.

    // ---------------- Phase 2: basis via LDS scatter (r5, validated) -------
    {
        const int sr = tid >> 5;             // chunk-local row 0..7
        const int f0 = tid & 31;
        for (int c = 0; c < NCHUNK; ++c) {
            const float* xrow = xTf + (c * CHROWS + sr) * XT_F;
            float* basr = bas + sr * BAS_F;
#pragma unroll
            for (int m = 0; m < 4; ++m) {
                int f = f0 + 32 * m;
                float x = xrow[f];
                int s;
                float w0, w1, w2, w3;
                bw(x, s, w0, w1, w2, w3);
                float* bp = basr + f * NBAS + s;
                if (s <= 5)           bp[0]  = w0;
                if (s >= 1 && s <= 6) bp[-1] = w1;
                if (s >= 2 && s <= 7) bp[-2] = w2;
                if (s >= 3)           bp[-3] = w3;   // s<=8 always
            }
            __syncthreads();

            float* ob = out + (size_t)(row0 + c * CHROWS) * OUTW;
#pragma unroll
            for (int k = 0; k < 6; ++k) {
                int idx = k * 256 + tid;     // f4 idx in chunk, 0..1535
                int r = idx / 192;           // 192 f4 per row
                int j = idx - r * 192;
                f4v v = bas4[idx];
                __builtin_nontemporal_store(v, (f4v*)(ob + (size_t)r * OUTW + 4 * j));
                bas4[idx] = z4;
            }
            __syncthreads();
        }
    }
}

// ---------------------------------------------------------------------------
extern "C" void kernel_launch(void* const* d_in, const int* in_sizes, int n_in,
                              void* d_out, int out_size, void* d_ws, size_t ws_size,
                              hipStream_t stream) {
    const float* X = (const float*)d_in[0];
    const float* W = (const float*)d_in[1];
    float* out = (float*)d_out;
    _Float16* ST = (_Float16*)d_ws;   // 32 KB scratch: sigmoid(W)^T in fp16

    sigmoid_kT<<<(DIM * DIM) / 256, 256, 0, stream>>>(W, ST);
    kan_main<<<BATCH / ROWS_PER_TILE, 256, 0, stream>>>(X, ST, out);
}